// Round 16
// baseline (112.562 us; speedup 1.0000x reference)
//
#include <hip/hip_runtime.h>
#include <hip/hip_bf16.h>
#include <cstdint>
#include <cstddef>

#define B_     16
#define S_     577
#define SP_    584              // padded per-batch seq: 584 = 73*8, 16*584 = 73*128
#define HID_   768
#define H_     12
#define D_     64
#define NKEEP_ 576
#define MP_    (B_ * SP_)       // 9344 padded rows = 73 * 128 (no tail)
#define NP4    (MP_ * HID_ / 4) // 1,794,048 uint2 groups

typedef __bf16 bf16;
typedef __bf16 bf16x8 __attribute__((ext_vector_type(8)));
typedef float  f32x4  __attribute__((ext_vector_type(4)));

__device__ __forceinline__ void gload16(const bf16* g, bf16* l) {
    __builtin_amdgcn_global_load_lds(
        (const __attribute__((address_space(1))) unsigned int*)g,
        (__attribute__((address_space(3))) unsigned int*)l, 16, 0, 0);
}

__device__ __forceinline__ float fexp2(float x) {
#if __has_builtin(__builtin_amdgcn_exp2f)
    return __builtin_amdgcn_exp2f(x);
#else
    return exp2f(x);
#endif
}

// counted-vmcnt barrier for the DEPTH-3 gemm pipeline ONLY (stage targets a
// buffer >=2 steps from any reader). lgkmcnt(0) REQUIRED (R4 race).
// Depth-2 LDS-DMA with this barrier is BANNED (R11).
#define WAITBAR(N) asm volatile("s_waitcnt vmcnt(" #N ") lgkmcnt(0)\n\ts_barrier" ::: "memory")

// attn barrier: full LDS drain (lgkmcnt(0), identical to __syncthreads for all
// ds ops) but leaves the OTHER reg-pair's 2 global->VGPR loads in flight.
// Safe vs R11's ban: floating ops touch only private VGPRs, not shared LDS
// (the banned case was global_load_lds DMA, which writes LDS).
#define WAITBARA asm volatile("s_waitcnt vmcnt(2) lgkmcnt(0)\n\ts_barrier" ::: "memory")

// ---------------- K1: fused prep ----------------
__global__ __launch_bounds__(256) void k_prep(const float* __restrict__ hs,
                                              const float* __restrict__ Wq,
                                              const float* __restrict__ Wk,
                                              const float* __restrict__ Wv,
                                              const float* __restrict__ bq,
                                              const float* __restrict__ bk,
                                              const float* __restrict__ bv,
                                              const int* __restrict__ qi,
                                              const int* __restrict__ ki,
                                              const int* __restrict__ vi,
                                              bf16* __restrict__ hs_bf,
                                              bf16* __restrict__ Wp_t,
                                              int* __restrict__ inv,
                                              float* __restrict__ bias_p) {
    __shared__ float tile[64][33];
    const int bid = blockIdx.x, t = threadIdx.x;
    if (bid < 54) {
        const int p = bid / 18;
        const int j0 = (bid % 18) * 32;
        const float* W  = (p == 0) ? Wq : (p == 1) ? Wk : Wv;
        const int* idx  = (p == 0) ? qi : (p == 1) ? ki : vi;
        bf16* dst = Wp_t + (size_t)p * HID_ * HID_;
        const int lj = t & 31, lk = t >> 5;
        const int sj = t >> 3, ke = (t & 7) * 8;
        const int c = idx[j0 + sj];
        for (int kt = 0; kt < HID_; kt += 64) {
            __syncthreads();
#pragma unroll
            for (int i = 0; i < 8; ++i)
                tile[lk + i * 8][lj] = W[(size_t)(kt + lk + i * 8) * NKEEP_ + j0 + lj];
            __syncthreads();
            union { bf16 h[8]; bf16x8 v; } o;
#pragma unroll
            for (int i = 0; i < 8; ++i) o.h[i] = (bf16)tile[ke + i][sj];
            *reinterpret_cast<bf16x8*>(dst + (size_t)c * HID_ + kt + ke) = o.v;
        }
    } else if (bid == 54) {
        for (int i = t; i < 3 * HID_; i += 256) { inv[i] = -1; bias_p[i] = 0.0f; }
        __syncthreads();
        for (int i = t; i < 3 * NKEEP_; i += 256) {
            const int p = i / NKEEP_, j = i % NKEEP_;
            const int* src = (p == 0) ? qi : (p == 1) ? ki : vi;
            const float* bb = (p == 0) ? bq : (p == 1) ? bk : bv;
            const int c = src[j];
            inv[p * HID_ + c] = j;
            bias_p[p * HID_ + c] = bb[j];
        }
    } else {
        const int i = (bid - 55) * 256 + t;
        if (i < NP4) {
            const int row = i / 192;
            const int col = i - row * 192;
            const int b = row / SP_;
            const int s = row - b * SP_;
            uint2 ov = {0u, 0u};
            if (s < S_) {
                float4 v = reinterpret_cast<const float4*>(hs)[((size_t)(b * S_ + s)) * 192 + col];
                union { bf16 h[4]; uint2 u; } o;
                o.h[0] = (bf16)v.x; o.h[1] = (bf16)v.y;
                o.h[2] = (bf16)v.z; o.h[3] = (bf16)v.w;
                ov = o.u;
            }
            reinterpret_cast<uint2*>(hs_bf)[(size_t)row * 192 + col] = ov;
        }
    }
}

// ---------------- K4: projection GEMM (128x256 block); depth-3 counted-vmcnt ----------------
#define BM 128
#define BN 256
#define BK 32
#define BUFE 12288        // elems per pipeline buffer: A 4096 + B 8192

__global__ __launch_bounds__(256, 2) void k_gemm(const bf16* __restrict__ X,
                                                 const bf16* __restrict__ Wp_t,
                                                 const float* __restrict__ bias_p,
                                                 bf16* __restrict__ Qo, bf16* __restrict__ Ko,
                                                 bf16* __restrict__ Vt) {
    __shared__ bf16 smem[3 * BUFE];   // 72KB; epilogue reuses [0..16639]

    // bijective XCD-chunked decode (657 = 8*82 + 1)
    const int xcd = blockIdx.x & 7, pos = blockIdx.x >> 3;
    const int L = xcd * 82 + (xcd > 0 ? 1 : 0) + pos;
    const int m0 = (L / 9) * BM;
    const int np = L % 9;
    const int n0 = (np % 3) * BN;
    const int p  = np / 3;

    const bf16* Wbase = Wp_t + (size_t)p * HID_ * HID_;
    const float osc = (p == 0) ? 0.125f * 1.44269504f : 1.0f;

    const int t = threadIdx.x;
    const int wid = t >> 6, lane = t & 63;
    const int wr = wid >> 1, wc = wid & 1;
    const int lrow = lane & 15, g = lane >> 4, lk = (lane >> 4) * 8;
    const int srow = lane >> 2, scol = (lane & 3) * 8;

    const bf16* Xs = X + (size_t)m0 * HID_;
    const bf16* Ws = Wbase + (size_t)n0 * HID_;

    f32x4 acc[4][8] = {};

#define STAGE(buf, kk)                                                          \
    {                                                                           \
        _Pragma("unroll")                                                       \
        for (int i_ = 0; i_ < 2; ++i_) {                                        \
            const int c_ = wid * 2 + i_;                                        \
            gload16(Xs + (size_t)(c_ * 16 + srow) * HID_ + (kk) + scol,         \
                    smem + (buf) * BUFE + c_ * 512);                            \
        }                                                                       \
        _Pragma("unroll")                                                       \
        for (int i_ = 0; i_ < 4; ++i_) {                                        \
            const int c_ = wid * 4 + i_;                                        \
            gload16(Ws + (size_t)(c_ * 16 + srow) * HID_ + (kk) + scol,         \
                    smem + (buf) * BUFE + 4096 + c_ * 512);                     \
        }                                                                       \
    }

#define COMPUTE(buf)                                                            \
    {                                                                           \
        const bf16* As_ = smem + (buf) * BUFE;                                  \
        const bf16* Bs_ = As_ + 4096;                                           \
        bf16x8 af[4], bfr[8];                                                   \
        _Pragma("unroll")                                                       \
        for (int m = 0; m < 4; ++m)                                             \
            af[m] = *reinterpret_cast<const bf16x8*>(                           \
                &As_[(wr * 64 + m * 16 + lrow) * BK + lk]);                     \
        _Pragma("unroll")                                                       \
        for (int n = 0; n < 8; ++n)                                             \
            bfr[n] = *reinterpret_cast<const bf16x8*>(                          \
                &Bs_[(wc * 128 + n * 16 + lrow) * BK + lk]);                    \
        _Pragma("unroll")                                                       \
        for (int m = 0; m < 4; ++m)                                             \
            _Pragma("unroll")                                                   \
            for (int n = 0; n < 8; ++n)                                         \
                acc[m][n] = __builtin_amdgcn_mfma_f32_16x16x32_bf16(            \
                    af[m], bfr[n], acc[m][n], 0, 0, 0);                         \
    }

    STAGE(0, 0)
    STAGE(1, BK)
    WAITBAR(6);

    int kk_next = 2 * BK;
    for (int u = 0; u < 7; ++u) {          // t = 0..20
#pragma unroll
        for (int j = 0; j < 3; ++j) {
            STAGE((j + 2) % 3, kk_next)    // stage tile t+2
            COMPUTE(j)                     // compute tile t
            WAITBAR(6);                    // tile t+1 landed; t+2 in flight
            kk_next += BK;
        }
    }
    STAGE(2, 23 * BK)
    COMPUTE(0)
    WAITBAR(6);
    COMPUTE(1)
    WAITBAR(0);
    COMPUTE(2)
#undef STAGE
#undef COMPUTE

    float bias_n[8];
#pragma unroll
    for (int n = 0; n < 8; ++n)
        bias_n[n] = bias_p[p * HID_ + n0 + wc * 128 + n * 16 + lrow];

    const int rowl = t >> 2, cq = t & 3;
#pragma unroll
    for (int half = 0; half < 2; ++half) {
        __syncthreads();
        if (wr == half) {
#pragma unroll
            for (int n = 0; n < 8; ++n)
#pragma unroll
                for (int m = 0; m < 4; ++m)
#pragma unroll
                    for (int r = 0; r < 4; ++r)
                        smem[(m * 16 + g * 4 + r) * 260 + wc * 128 + n * 16 + lrow] =
                            (bf16)((acc[m][n][r] + bias_n[n]) * osc);
        }
        __syncthreads();
        const int grow0 = m0 + half * 64;
        if (p < 2) {
            bf16* Obase = (p == 0) ? Qo : Ko;
            const int grow = grow0 + rowl;
            const int b = grow / SP_, s = grow - b * SP_;
#pragma unroll
            for (int i = 0; i < 8; ++i) {
                const int c0 = i * 32 + cq * 8;
                bf16x8 v = *reinterpret_cast<const bf16x8*>(&smem[rowl * 260 + c0]);
                const int c = n0 + c0, h = c >> 6, d = c & 63;
                *reinterpret_cast<bf16x8*>(
                    &Obase[(((size_t)(b * H_ + h) * SP_) + s) * D_ + d]) = v;
            }
        } else {
            const int crow = n0 + t;
            bf16* vrow = Vt + (size_t)crow * MP_;
#pragma unroll
            for (int rg = 0; rg < 8; ++rg) {
                union { bf16 h8[8]; bf16x8 v; } pk;
#pragma unroll
                for (int i = 0; i < 8; ++i)
                    pk.h8[i] = smem[(rg * 8 + i) * 260 + t];
                *reinterpret_cast<bf16x8*>(&vrow[grow0 + rg * 8]) = pk.v;
            }
        }
    }
}

// ---------------- K5: flash attention; 2-deep reg prefetch + analytic key-576 ----------------
// R15 geometry (512 thr, 5 q-chunks x 128 rows, (512,4)); only change: K/V
// prefetch is 2 tiles deep via ping-pong reg pairs (kA/vA, kB/vB — named,
// rule #20), so each pair has ~2 compute phases (~800cy) to land before its
// LDS-write. Barrier = WAITBARA (full lgkmcnt drain; only reg-loads float).
#define KB2  64
#define VLD2 72
#define KVSZ (KB2 * VLD2)   // 4608 elems per buffer

__global__ __launch_bounds__(512, 4) void k_attn(const bf16* __restrict__ Q,
                                                 const bf16* __restrict__ K,
                                                 const bf16* __restrict__ Vt,
                                                 const int* __restrict__ inv,
                                                 float* __restrict__ out) {
    __shared__ bf16 Ksm[2][KVSZ];
    __shared__ bf16 Vsm[2][KVSZ];   // V^T: [d][key] linear (stride 72)
    __shared__ bf16 Klast[64];      // K[576][:]
    __shared__ bf16 Vlast[64];      // V[576][:] (gathered from Vt)

    const int bid = blockIdx.x;
    const int bh = bid % (B_ * H_);           // same-bh blocks land on same XCD
    const int q0 = (bid / (B_ * H_)) * 128;
    const int t = threadIdx.x, wid = t >> 6, lane = t & 63;
    const int lcol = lane & 15, g = lane >> 4;
    const int b = bh / H_, h = bh % H_;

    const bf16* Qb = Q + (size_t)bh * SP_ * D_;
    const bf16* Kb = K + (size_t)bh * SP_ * D_;

    // key-576 correction data FIRST: its ds_write forces a deep vmcnt wait, so
    // issue+retire it before the pipelined prefetch loads exist.
    if (t < 8)
        *reinterpret_cast<bf16x8*>(Klast + t * 8) =
            *reinterpret_cast<const bf16x8*>(Kb + (size_t)576 * D_ + t * 8);
    else if (t >= 64 && t < 128)
        Vlast[t - 64] = Vt[(size_t)(h * D_ + (t - 64)) * MP_ + (size_t)b * SP_ + 576];

    const int qrow = q0 + wid * 16 + lcol;    // 0..639 (pad rows masked at out)
    bf16x8 qf0 = *reinterpret_cast<const bf16x8*>(Qb + (size_t)qrow * D_ + g * 8);
    bf16x8 qf1 = *reinterpret_cast<const bf16x8*>(Qb + (size_t)qrow * D_ + 32 + g * 8);

    const int key_t = t >> 3;
    const int ch_t = (t & 7) * 8;
    const bf16* Vrow = Vt + (size_t)(h * D_ + key_t) * MP_ + (size_t)b * SP_;

    float lrun = 0.f;
    f32x4 oT[4] = {};

    // 2-deep prefetch: pair A = tile 0, pair B = tile 1 (4 loads in flight)
    bf16x8 kA = *reinterpret_cast<const bf16x8*>(Kb + (size_t)key_t * D_ + ch_t);
    bf16x8 vA = *reinterpret_cast<const bf16x8*>(Vrow + ch_t);
    bf16x8 kB = *reinterpret_cast<const bf16x8*>(Kb + (size_t)(64 + key_t) * D_ + ch_t);
    bf16x8 vB = *reinterpret_cast<const bf16x8*>(Vrow + 64 + ch_t);

    int cur = 0;

#define ATTN_COMPUTE                                                            \
    {                                                                           \
        f32x4 sv[4];                                                            \
        __builtin_amdgcn_s_setprio(1);                                          \
        _Pragma("unroll")                                                       \
        for (int ks = 0; ks < 4; ++ks) {                                        \
            const bf16* kr = &Ksm[cur][(ks * 16 + lcol) * VLD2];                \
            bf16x8 kf0 = *reinterpret_cast<const bf16x8*>(kr + g * 8);          \
            bf16x8 kf1 = *reinterpret_cast<const bf16x8*>(kr + 32 + g * 8);     \
            f32x4 z = {};                                                       \
            z = __builtin_amdgcn_mfma_f32_16x16x32_bf16(kf0, qf0, z, 0, 0, 0);  \
            z = __builtin_amdgcn_mfma_f32_16x16x32_bf16(kf1, qf1, z, 0, 0, 0);  \
            sv[ks] = z;                                                         \
        }                                                                       \
        __builtin_amdgcn_s_setprio(0);                                          \
        union { bf16 h[16]; bf16x8 v[2]; } pu;                                  \
        float rs = 0.f;                                                         \
        _Pragma("unroll")                                                       \
        for (int ks = 0; ks < 4; ++ks)                                          \
            _Pragma("unroll")                                                   \
            for (int r = 0; r < 4; ++r) {                                       \
                float pv = fexp2(sv[ks][r]);                                    \
                rs += pv;                                                       \
                pu.h[ks * 4 + r] = (bf16)pv;                                    \
            }                                                                   \
        lrun += rs;                                                             \
        __builtin_amdgcn_s_setprio(1);                                          \
        _Pragma("unroll")                                                       \
        for (int kh = 0; kh < 2; ++kh) {                                        \
            _Pragma("unroll")                                                   \
            for (int tt = 0; tt < 4; ++tt) {                                    \
                const int d = tt * 16 + lcol;                                   \
                const bf16* vr = &Vsm[cur][d * VLD2 + kh * 32 + 4 * g];         \
                union { uint2 u[2]; bf16x8 v8; } vf;                            \
                vf.u[0] = *reinterpret_cast<const uint2*>(vr);                  \
                vf.u[1] = *reinterpret_cast<const uint2*>(vr + 16);             \
                oT[tt] = __builtin_amdgcn_mfma_f32_16x16x32_bf16(vf.v8, pu.v[kh], oT[tt], 0, 0, 0); \
            }                                                                   \
        }                                                                       \
        __builtin_amdgcn_s_setprio(0);                                          \
        cur ^= 1;                                                               \
    }

// write tile from reg pair; counted barrier; reload pair with tile (nk0);
// compute. Tile-9 reload (nk0=576..639) lands in the proven PAD slack and is
// never consumed (same overrun as R15's unconditional prefetch).
#define ATTN_STEP(KR, VR, nk0)                                                  \
    {                                                                           \
        *reinterpret_cast<bf16x8*>(&Ksm[cur][key_t * VLD2 + ch_t]) = KR;        \
        *reinterpret_cast<bf16x8*>(&Vsm[cur][key_t * VLD2 + ch_t]) = VR;        \
        WAITBARA;                                                               \
        KR = *reinterpret_cast<const bf16x8*>(Kb + (size_t)((nk0) + key_t) * D_ + ch_t); \
        VR = *reinterpret_cast<const bf16x8*>(Vrow + (nk0) + ch_t);             \
        ATTN_COMPUTE                                                            \
    }

    // tiles 0..7 (pairs), each reg pair reloaded 2 tiles ahead
    for (int pp = 0; pp < 4; ++pp) {
        ATTN_STEP(kA, vA, (2 * pp + 2) * KB2)   // tile 2pp   (A)
        ATTN_STEP(kB, vB, (2 * pp + 3) * KB2)   // tile 2pp+1 (B)
    }
    // tile 8 (A holds it; B holds garbage tile 9, never used)
    {
        *reinterpret_cast<bf16x8*>(&Ksm[cur][key_t * VLD2 + ch_t]) = kA;
        *reinterpret_cast<bf16x8*>(&Vsm[cur][key_t * VLD2 + ch_t]) = vA;
        WAITBARA;
        ATTN_COMPUTE
    }
#undef ATTN_STEP
#undef ATTN_COMPUTE

    // analytic key-576 correction (R14/R15-verified)
    {
        bf16x8 kl0 = *reinterpret_cast<const bf16x8*>(Klast + g * 8);
        bf16x8 kl1 = *reinterpret_cast<const bf16x8*>(Klast + 32 + g * 8);
        float part = 0.f;
#pragma unroll
        for (int i = 0; i < 8; ++i)
            part += (float)qf0[i] * (float)kl0[i] + (float)qf1[i] * (float)kl1[i];
        part += __shfl_xor(part, 16);
        part += __shfl_xor(part, 32);
        float p5 = fexp2(part);
        if (g == 0) lrun += p5;   // count the key once per q (4 g-copies)
#pragma unroll
        for (int tt = 0; tt < 4; ++tt)
#pragma unroll
            for (int r = 0; r < 4; ++r)
                oT[tt][r] += p5 * (float)Vlast[tt * 16 + g * 4 + r];
    }

    lrun += __shfl_xor(lrun, 16);
    lrun += __shfl_xor(lrun, 32);

    if (qrow < S_) {
        const int* invv = inv + 2 * HID_;
        float invl = 1.0f / lrun;
        float* orow = out + ((size_t)b * S_ + qrow) * NKEEP_;
#pragma unroll
        for (int tt = 0; tt < 4; ++tt)
#pragma unroll
            for (int r = 0; r < 4; ++r) {
                int d = tt * 16 + g * 4 + r;
                int j = invv[h * D_ + d];
                if (j >= 0) orow[j] = oT[tt][r] * invl;
            }
    }
}

// ---------------- launch ----------------
extern "C" void kernel_launch(void* const* d_in, const int* in_sizes, int n_in,
                              void* d_out, int out_size, void* d_ws, size_t ws_size,
                              hipStream_t stream) {
    const float* hs = (const float*)d_in[0];
    const float* Wq = (const float*)d_in[1];
    const float* bq = (const float*)d_in[2];
    const float* Wk = (const float*)d_in[3];
    const float* bk = (const float*)d_in[4];
    const float* Wv = (const float*)d_in[5];
    const float* bv = (const float*)d_in[6];
    const int* qi = (const int*)d_in[7];
    const int* ki = (const int*)d_in[8];
    const int* vi = (const int*)d_in[9];
    float* out = (float*)d_out;

    char* ws = (char*)d_ws;
    size_t off = 0;
    const size_t PAD = 8192;   // over-read slack for unguarded padded loads
    bf16* hs_bf = (bf16*)(ws + off); off += (size_t)MP_ * HID_ * 2 + PAD;
    bf16* Wp_t  = (bf16*)(ws + off); off += (size_t)3 * HID_ * HID_ * 2;
    float* bias_p = (float*)(ws + off); off += 3 * HID_ * 4;
    int* inv = (int*)(ws + off); off += 3 * HID_ * 4;
    bf16* Qw = (bf16*)(ws + off); off += (size_t)B_ * H_ * SP_ * D_ * 2 + PAD;
    bf16* Kw = (bf16*)(ws + off); off += (size_t)B_ * H_ * SP_ * D_ * 2 + PAD;
    bf16* Vt = (bf16*)(ws + off); off += (size_t)HID_ * MP_ * 2 + PAD;

    hipMemsetAsync(Wp_t, 0, (size_t)3 * HID_ * HID_ * 2, stream);
    const int nprep = 55 + (NP4 + 255) / 256;
    k_prep<<<nprep, 256, 0, stream>>>(hs, Wq, Wk, Wv, bq, bk, bv, qi, ki, vi,
                                      hs_bf, Wp_t, inv, bias_p);
    k_gemm<<<657, 256, 0, stream>>>(hs_bf, Wp_t, bias_p, Qw, Kw, Vt);
    k_attn<<<5 * B_ * H_, 512, 0, stream>>>(Qw, Kw, Vt, inv, out);
}

// Round 17
// 107.440 us; speedup vs baseline: 1.0477x; 1.0477x over previous
//
#include <hip/hip_runtime.h>
#include <hip/hip_bf16.h>
#include <cstdint>
#include <cstddef>

#define B_     16
#define S_     577
#define SP_    584              // padded per-batch seq: 584 = 73*8, 16*584 = 73*128
#define HID_   768
#define H_     12
#define D_     64
#define NKEEP_ 576
#define MP_    (B_ * SP_)       // 9344 padded rows = 73 * 128 (no tail)
#define NP4    (MP_ * HID_ / 4) // 1,794,048 uint2 groups

typedef __bf16 bf16;
typedef __bf16 bf16x8 __attribute__((ext_vector_type(8)));
typedef float  f32x4  __attribute__((ext_vector_type(4)));

__device__ __forceinline__ void gload16(const bf16* g, bf16* l) {
    __builtin_amdgcn_global_load_lds(
        (const __attribute__((address_space(1))) unsigned int*)g,
        (__attribute__((address_space(3))) unsigned int*)l, 16, 0, 0);
}

__device__ __forceinline__ float fexp2(float x) {
#if __has_builtin(__builtin_amdgcn_exp2f)
    return __builtin_amdgcn_exp2f(x);
#else
    return exp2f(x);
#endif
}

// counted-vmcnt barrier for the DEPTH-3 pipeline ONLY (stage targets a buffer
// >=2 steps from any reader -> a one-barrier-early DMA is still harmless).
// lgkmcnt(0) REQUIRED (R4 race). Depth-2 with this barrier is BANNED (R11).
#define WAITBAR(N) asm volatile("s_waitcnt vmcnt(" #N ") lgkmcnt(0)\n\ts_barrier" ::: "memory")

// ---------------- K1: fused prep ----------------
__global__ __launch_bounds__(256) void k_prep(const float* __restrict__ hs,
                                              const float* __restrict__ Wq,
                                              const float* __restrict__ Wk,
                                              const float* __restrict__ Wv,
                                              const float* __restrict__ bq,
                                              const float* __restrict__ bk,
                                              const float* __restrict__ bv,
                                              const int* __restrict__ qi,
                                              const int* __restrict__ ki,
                                              const int* __restrict__ vi,
                                              bf16* __restrict__ hs_bf,
                                              bf16* __restrict__ Wp_t,
                                              int* __restrict__ inv,
                                              float* __restrict__ bias_p) {
    __shared__ float tile[64][33];
    const int bid = blockIdx.x, t = threadIdx.x;
    if (bid < 54) {
        const int p = bid / 18;
        const int j0 = (bid % 18) * 32;
        const float* W  = (p == 0) ? Wq : (p == 1) ? Wk : Wv;
        const int* idx  = (p == 0) ? qi : (p == 1) ? ki : vi;
        bf16* dst = Wp_t + (size_t)p * HID_ * HID_;
        const int lj = t & 31, lk = t >> 5;
        const int sj = t >> 3, ke = (t & 7) * 8;
        const int c = idx[j0 + sj];
        for (int kt = 0; kt < HID_; kt += 64) {
            __syncthreads();
#pragma unroll
            for (int i = 0; i < 8; ++i)
                tile[lk + i * 8][lj] = W[(size_t)(kt + lk + i * 8) * NKEEP_ + j0 + lj];
            __syncthreads();
            union { bf16 h[8]; bf16x8 v; } o;
#pragma unroll
            for (int i = 0; i < 8; ++i) o.h[i] = (bf16)tile[ke + i][sj];
            *reinterpret_cast<bf16x8*>(dst + (size_t)c * HID_ + kt + ke) = o.v;
        }
    } else if (bid == 54) {
        for (int i = t; i < 3 * HID_; i += 256) { inv[i] = -1; bias_p[i] = 0.0f; }
        __syncthreads();
        for (int i = t; i < 3 * NKEEP_; i += 256) {
            const int p = i / NKEEP_, j = i % NKEEP_;
            const int* src = (p == 0) ? qi : (p == 1) ? ki : vi;
            const float* bb = (p == 0) ? bq : (p == 1) ? bk : bv;
            const int c = src[j];
            inv[p * HID_ + c] = j;
            bias_p[p * HID_ + c] = bb[j];
        }
    } else {
        const int i = (bid - 55) * 256 + t;
        if (i < NP4) {
            const int row = i / 192;
            const int col = i - row * 192;
            const int b = row / SP_;
            const int s = row - b * SP_;
            uint2 ov = {0u, 0u};
            if (s < S_) {
                float4 v = reinterpret_cast<const float4*>(hs)[((size_t)(b * S_ + s)) * 192 + col];
                union { bf16 h[4]; uint2 u; } o;
                o.h[0] = (bf16)v.x; o.h[1] = (bf16)v.y;
                o.h[2] = (bf16)v.z; o.h[3] = (bf16)v.w;
                ov = o.u;
            }
            reinterpret_cast<uint2*>(hs_bf)[(size_t)row * 192 + col] = ov;
        }
    }
}

// ---------------- K4: projection GEMM (128x256 block); depth-3 counted-vmcnt ----------------
#define BM 128
#define BN 256
#define BK 32
#define BUFE 12288        // elems per pipeline buffer: A 4096 + B 8192

__global__ __launch_bounds__(256, 2) void k_gemm(const bf16* __restrict__ X,
                                                 const bf16* __restrict__ Wp_t,
                                                 const float* __restrict__ bias_p,
                                                 bf16* __restrict__ Qo, bf16* __restrict__ Ko,
                                                 bf16* __restrict__ Vt) {
    __shared__ bf16 smem[3 * BUFE];   // 72KB; epilogue reuses [0..16639]

    // bijective XCD-chunked decode (657 = 8*82 + 1)
    const int xcd = blockIdx.x & 7, pos = blockIdx.x >> 3;
    const int L = xcd * 82 + (xcd > 0 ? 1 : 0) + pos;
    const int m0 = (L / 9) * BM;
    const int np = L % 9;
    const int n0 = (np % 3) * BN;
    const int p  = np / 3;

    const bf16* Wbase = Wp_t + (size_t)p * HID_ * HID_;
    const float osc = (p == 0) ? 0.125f * 1.44269504f : 1.0f;

    const int t = threadIdx.x;
    const int wid = t >> 6, lane = t & 63;
    const int wr = wid >> 1, wc = wid & 1;
    const int lrow = lane & 15, g = lane >> 4, lk = (lane >> 4) * 8;
    const int srow = lane >> 2, scol = (lane & 3) * 8;

    const bf16* Xs = X + (size_t)m0 * HID_;
    const bf16* Ws = Wbase + (size_t)n0 * HID_;

    f32x4 acc[4][8] = {};

#define STAGE(buf, kk)                                                          \
    {                                                                           \
        _Pragma("unroll")                                                       \
        for (int i_ = 0; i_ < 2; ++i_) {                                        \
            const int c_ = wid * 2 + i_;                                        \
            gload16(Xs + (size_t)(c_ * 16 + srow) * HID_ + (kk) + scol,         \
                    smem + (buf) * BUFE + c_ * 512);                            \
        }                                                                       \
        _Pragma("unroll")                                                       \
        for (int i_ = 0; i_ < 4; ++i_) {                                        \
            const int c_ = wid * 4 + i_;                                        \
            gload16(Ws + (size_t)(c_ * 16 + srow) * HID_ + (kk) + scol,         \
                    smem + (buf) * BUFE + 4096 + c_ * 512);                     \
        }                                                                       \
    }

#define COMPUTE(buf)                                                            \
    {                                                                           \
        const bf16* As_ = smem + (buf) * BUFE;                                  \
        const bf16* Bs_ = As_ + 4096;                                           \
        bf16x8 af[4], bfr[8];                                                   \
        _Pragma("unroll")                                                       \
        for (int m = 0; m < 4; ++m)                                             \
            af[m] = *reinterpret_cast<const bf16x8*>(                           \
                &As_[(wr * 64 + m * 16 + lrow) * BK + lk]);                     \
        _Pragma("unroll")                                                       \
        for (int n = 0; n < 8; ++n)                                             \
            bfr[n] = *reinterpret_cast<const bf16x8*>(                          \
                &Bs_[(wc * 128 + n * 16 + lrow) * BK + lk]);                    \
        _Pragma("unroll")                                                       \
        for (int m = 0; m < 4; ++m)                                             \
            _Pragma("unroll")                                                   \
            for (int n = 0; n < 8; ++n)                                         \
                acc[m][n] = __builtin_amdgcn_mfma_f32_16x16x32_bf16(            \
                    af[m], bfr[n], acc[m][n], 0, 0, 0);                         \
    }

    STAGE(0, 0)
    STAGE(1, BK)
    WAITBAR(6);

    int kk_next = 2 * BK;
    for (int u = 0; u < 7; ++u) {          // t = 0..20
#pragma unroll
        for (int j = 0; j < 3; ++j) {
            STAGE((j + 2) % 3, kk_next)    // stage tile t+2
            COMPUTE(j)                     // compute tile t
            WAITBAR(6);                    // tile t+1 landed; t+2 in flight
            kk_next += BK;
        }
    }
    STAGE(2, 23 * BK)
    COMPUTE(0)
    WAITBAR(6);
    COMPUTE(1)
    WAITBAR(0);
    COMPUTE(2)
#undef STAGE
#undef COMPUTE

    float bias_n[8];
#pragma unroll
    for (int n = 0; n < 8; ++n)
        bias_n[n] = bias_p[p * HID_ + n0 + wc * 128 + n * 16 + lrow];

    const int rowl = t >> 2, cq = t & 3;
#pragma unroll
    for (int half = 0; half < 2; ++half) {
        __syncthreads();
        if (wr == half) {
#pragma unroll
            for (int n = 0; n < 8; ++n)
#pragma unroll
                for (int m = 0; m < 4; ++m)
#pragma unroll
                    for (int r = 0; r < 4; ++r)
                        smem[(m * 16 + g * 4 + r) * 260 + wc * 128 + n * 16 + lrow] =
                            (bf16)((acc[m][n][r] + bias_n[n]) * osc);
        }
        __syncthreads();
        const int grow0 = m0 + half * 64;
        if (p < 2) {
            bf16* Obase = (p == 0) ? Qo : Ko;
            const int grow = grow0 + rowl;
            const int b = grow / SP_, s = grow - b * SP_;
#pragma unroll
            for (int i = 0; i < 8; ++i) {
                const int c0 = i * 32 + cq * 8;
                bf16x8 v = *reinterpret_cast<const bf16x8*>(&smem[rowl * 260 + c0]);
                const int c = n0 + c0, h = c >> 6, d = c & 63;
                *reinterpret_cast<bf16x8*>(
                    &Obase[(((size_t)(b * H_ + h) * SP_) + s) * D_ + d]) = v;
            }
        } else {
            const int crow = n0 + t;
            bf16* vrow = Vt + (size_t)crow * MP_;
#pragma unroll
            for (int rg = 0; rg < 8; ++rg) {
                union { bf16 h8[8]; bf16x8 v; } pk;
#pragma unroll
                for (int i = 0; i < 8; ++i)
                    pk.h8[i] = smem[(rg * 8 + i) * 260 + t];
                *reinterpret_cast<bf16x8*>(&vrow[grow0 + rg * 8]) = pk.v;
            }
        }
    }
}

// ---------------- K5: flash attention; 9 branch-free tiles + analytic key-576 ----------------
// R13 geometry (512 threads, 5 q-chunks x 128 rows, __launch_bounds__(512,4))
// with the peeled 10th tile replaced by the R14-verified analytic correction.
#define KB2  64
#define VLD2 72
#define KVSZ (KB2 * VLD2)   // 4608 elems per buffer

__global__ __launch_bounds__(512, 4) void k_attn(const bf16* __restrict__ Q,
                                                 const bf16* __restrict__ K,
                                                 const bf16* __restrict__ Vt,
                                                 const int* __restrict__ inv,
                                                 float* __restrict__ out) {
    __shared__ bf16 Ksm[2][KVSZ];
    __shared__ bf16 Vsm[2][KVSZ];   // V^T: [d][key] linear (stride 72)
    __shared__ bf16 Klast[64];      // K[576][:]
    __shared__ bf16 Vlast[64];      // V[576][:] (gathered from Vt)

    const int bid = blockIdx.x;
    const int bh = bid % (B_ * H_);           // same-bh blocks land on same XCD
    const int q0 = (bid / (B_ * H_)) * 128;
    const int t = threadIdx.x, wid = t >> 6, lane = t & 63;
    const int lcol = lane & 15, g = lane >> 4;
    const int b = bh / H_, h = bh % H_;

    const bf16* Qb = Q + (size_t)bh * SP_ * D_;
    const bf16* Kb = K + (size_t)bh * SP_ * D_;

    const int qrow = q0 + wid * 16 + lcol;    // 0..639 (pad rows masked at out)
    bf16x8 qf0 = *reinterpret_cast<const bf16x8*>(Qb + (size_t)qrow * D_ + g * 8);
    bf16x8 qf1 = *reinterpret_cast<const bf16x8*>(Qb + (size_t)qrow * D_ + 32 + g * 8);

    const int key_t = t >> 3;
    const int ch_t = (t & 7) * 8;
    const bf16* Vrow = Vt + (size_t)(h * D_ + key_t) * MP_ + (size_t)b * SP_;

    float lrun = 0.f;
    f32x4 oT[4] = {};

    bf16x8 kreg = *reinterpret_cast<const bf16x8*>(Kb + (size_t)key_t * D_ + ch_t);
    bf16x8 vreg = *reinterpret_cast<const bf16x8*>(Vrow + ch_t);

    // key-576 data for the analytic correction (covered by the first barrier)
    if (t < 8)
        *reinterpret_cast<bf16x8*>(Klast + t * 8) =
            *reinterpret_cast<const bf16x8*>(Kb + (size_t)576 * D_ + t * 8);
    else if (t >= 64 && t < 128)
        Vlast[t - 64] = Vt[(size_t)(h * D_ + (t - 64)) * MP_ + (size_t)b * SP_ + 576];

    int cur = 0;
    // main loop: exactly 9 tiles (keys 0..575), branch-free, unconditional
    // prefetch (last prefetch reads pad slack; regs discarded)
    for (int k0 = 0; k0 < 576; k0 += KB2) {
        *reinterpret_cast<bf16x8*>(&Ksm[cur][key_t * VLD2 + ch_t]) = kreg;
        *reinterpret_cast<bf16x8*>(&Vsm[cur][key_t * VLD2 + ch_t]) = vreg;
        __syncthreads();   // single barrier per tile (full drain)

        kreg = *reinterpret_cast<const bf16x8*>(Kb + (size_t)(k0 + KB2 + key_t) * D_ + ch_t);
        vreg = *reinterpret_cast<const bf16x8*>(Vrow + k0 + KB2 + ch_t);

        // scores S^T = K . Q^T (log2 units)
        f32x4 sv[4];
        __builtin_amdgcn_s_setprio(1);
#pragma unroll
        for (int ks = 0; ks < 4; ++ks) {
            const bf16* kr = &Ksm[cur][(ks * 16 + lcol) * VLD2];
            bf16x8 kf0 = *reinterpret_cast<const bf16x8*>(kr + g * 8);
            bf16x8 kf1 = *reinterpret_cast<const bf16x8*>(kr + 32 + g * 8);
            f32x4 z = {};
            z = __builtin_amdgcn_mfma_f32_16x16x32_bf16(kf0, qf0, z, 0, 0, 0);
            z = __builtin_amdgcn_mfma_f32_16x16x32_bf16(kf1, qf1, z, 0, 0, 0);
            sv[ks] = z;
        }
        __builtin_amdgcn_s_setprio(0);

        // softmax numerators: p = 2^s' (no max tracking, no cross-lane ops)
        union { bf16 h[16]; bf16x8 v[2]; } pu;
        float rs = 0.f;
#pragma unroll
        for (int ks = 0; ks < 4; ++ks)
#pragma unroll
            for (int r = 0; r < 4; ++r) {
                float pv = fexp2(sv[ks][r]);
                rs += pv;
                pu.h[ks * 4 + r] = (bf16)pv;   // slot (g,e): key = 32kh+16(e>>2)+4g+(e&3)
            }
        lrun += rs;

        // PV: O^T += V^T . P^T ; A-frag = two 8B reads from linear [d][key]
        __builtin_amdgcn_s_setprio(1);
#pragma unroll
        for (int kh = 0; kh < 2; ++kh) {
#pragma unroll
            for (int tt = 0; tt < 4; ++tt) {
                const int d = tt * 16 + lcol;
                const bf16* vr = &Vsm[cur][d * VLD2 + kh * 32 + 4 * g];
                union { uint2 u[2]; bf16x8 v8; } vf;
                vf.u[0] = *reinterpret_cast<const uint2*>(vr);
                vf.u[1] = *reinterpret_cast<const uint2*>(vr + 16);
                oT[tt] = __builtin_amdgcn_mfma_f32_16x16x32_bf16(vf.v8, pu.v[kh], oT[tt], 0, 0, 0);
            }
        }
        __builtin_amdgcn_s_setprio(0);
        cur ^= 1;
    }

    // analytic key-576 correction (replaces a whole masked tile; R14-verified):
    // s576 = dot(Q[q], K[576]) via resident qf regs; 4 g-lanes hold partials.
    {
        bf16x8 kl0 = *reinterpret_cast<const bf16x8*>(Klast + g * 8);
        bf16x8 kl1 = *reinterpret_cast<const bf16x8*>(Klast + 32 + g * 8);
        float part = 0.f;
#pragma unroll
        for (int i = 0; i < 8; ++i)
            part += (float)qf0[i] * (float)kl0[i] + (float)qf1[i] * (float)kl1[i];
        part += __shfl_xor(part, 16);
        part += __shfl_xor(part, 32);
        float p5 = fexp2(part);
        if (g == 0) lrun += p5;   // count the key once per q (4 g-copies)
#pragma unroll
        for (int tt = 0; tt < 4; ++tt)
#pragma unroll
            for (int r = 0; r < 4; ++r)
                oT[tt][r] += p5 * (float)Vlast[tt * 16 + g * 4 + r];
    }

    lrun += __shfl_xor(lrun, 16);
    lrun += __shfl_xor(lrun, 32);

    if (qrow < S_) {
        const int* invv = inv + 2 * HID_;
        float invl = 1.0f / lrun;
        float* orow = out + ((size_t)b * S_ + qrow) * NKEEP_;
#pragma unroll
        for (int tt = 0; tt < 4; ++tt)
#pragma unroll
            for (int r = 0; r < 4; ++r) {
                int d = tt * 16 + g * 4 + r;
                int j = invv[h * D_ + d];
                if (j >= 0) orow[j] = oT[tt][r] * invl;
            }
    }
}

// ---------------- launch ----------------
extern "C" void kernel_launch(void* const* d_in, const int* in_sizes, int n_in,
                              void* d_out, int out_size, void* d_ws, size_t ws_size,
                              hipStream_t stream) {
    const float* hs = (const float*)d_in[0];
    const float* Wq = (const float*)d_in[1];
    const float* bq = (const float*)d_in[2];
    const float* Wk = (const float*)d_in[3];
    const float* bk = (const float*)d_in[4];
    const float* Wv = (const float*)d_in[5];
    const float* bv = (const float*)d_in[6];
    const int* qi = (const int*)d_in[7];
    const int* ki = (const int*)d_in[8];
    const int* vi = (const int*)d_in[9];
    float* out = (float*)d_out;

    char* ws = (char*)d_ws;
    size_t off = 0;
    const size_t PAD = 8192;   // over-read slack for unguarded padded loads
    bf16* hs_bf = (bf16*)(ws + off); off += (size_t)MP_ * HID_ * 2 + PAD;
    bf16* Wp_t  = (bf16*)(ws + off); off += (size_t)3 * HID_ * HID_ * 2;
    float* bias_p = (float*)(ws + off); off += 3 * HID_ * 4;
    int* inv = (int*)(ws + off); off += 3 * HID_ * 4;
    bf16* Qw = (bf16*)(ws + off); off += (size_t)B_ * H_ * SP_ * D_ * 2 + PAD;
    bf16* Kw = (bf16*)(ws + off); off += (size_t)B_ * H_ * SP_ * D_ * 2 + PAD;
    bf16* Vt = (bf16*)(ws + off); off += (size_t)HID_ * MP_ * 2 + PAD;

    hipMemsetAsync(Wp_t, 0, (size_t)3 * HID_ * HID_ * 2, stream);
    const int nprep = 55 + (NP4 + 255) / 256;
    k_prep<<<nprep, 256, 0, stream>>>(hs, Wq, Wk, Wv, bq, bk, bv, qi, ki, vi,
                                      hs_bf, Wp_t, inv, bias_p);
    k_gemm<<<657, 256, 0, stream>>>(hs_bf, Wp_t, bias_p, Qw, Kw, Vt);
    k_attn<<<5 * B_ * H_, 512, 0, stream>>>(Qw, Kw, Vt, inv, out);
}